// Round 2
// baseline (1261.639 us; speedup 1.0000x reference)
//
#include <hip/hip_runtime.h>
#include <math.h>

#define V 30000
#define H 512
#define NB 16
#define NS 256
#define NJ 10
#define NT 8
#define NOPS 4
#define NR 160          // NJ*NB rows
#define EV 30720        // padded E row stride
#define NEGV -1e9f

typedef __attribute__((ext_vector_type(8))) short short8;
typedef __attribute__((ext_vector_type(4))) short short4v;
typedef __attribute__((ext_vector_type(4))) float f32x4;

__device__ inline float bf2f(unsigned short s) {
    union { unsigned int u; float f; } c; c.u = ((unsigned int)s) << 16;
    return c.f;
}
__device__ inline unsigned short f2bf(float f) {
    union { float f; unsigned int u; } c; c.f = f;
    unsigned int u = c.u;
    u += 0x7fffu + ((u >> 16) & 1u);   // RNE
    return (unsigned short)(u >> 16);
}
__device__ inline unsigned long long packkey(float f, int v) {
    union { float f; unsigned int u; } c; c.f = f;
    return ((unsigned long long)c.u << 32) | (unsigned int)(0x7FFFFFFF - v);
}

// ---------------- setup: convert emb_W to bf16 ----------------
__global__ void k_setup_emb(const float* __restrict__ emb, unsigned short* __restrict__ emb_bf, int n8) {
    int gid = blockIdx.x * 256 + threadIdx.x;
    if (gid >= n8) return;
    const float4* src = (const float4*)emb + (size_t)gid * 2;
    float4 a = src[0], b = src[1];
    short8 o;
    o[0] = (short)f2bf(a.x); o[1] = (short)f2bf(a.y); o[2] = (short)f2bf(a.z); o[3] = (short)f2bf(a.w);
    o[4] = (short)f2bf(b.x); o[5] = (short)f2bf(b.y); o[6] = (short)f2bf(b.z); o[7] = (short)f2bf(b.w);
    *(short8*)(emb_bf + (size_t)gid * 8) = o;
}

// ---------------- setup: W splits + initial w/h state ----------------
__global__ void k_setup_small(const float* __restrict__ Wih, const float* __restrict__ Whh,
    unsigned short* wih_hi, unsigned short* wih_lo, unsigned short* whh_hi, unsigned short* whh_lo,
    const float* __restrict__ slot, const float* __restrict__ ench,
    float* w_g, unsigned short* w_hi, unsigned short* w_lo,
    float* h_g, unsigned short* h_hi, unsigned short* h_lo)
{
    int gid = blockIdx.x * 256 + threadIdx.x;
    if (gid < 786432) {
        float v1 = Wih[gid];
        unsigned short hi = f2bf(v1);
        wih_hi[gid] = hi; wih_lo[gid] = f2bf(v1 - bf2f(hi));
        float v2 = Whh[gid];
        hi = f2bf(v2);
        whh_hi[gid] = hi; whh_lo[gid] = f2bf(v2 - bf2f(hi));
    } else {
        int i = gid - 786432;
        if (i < NR * H) {
            int jb = i >> 9, d = i & 511;
            int j = jb >> 4, b = jb & 15;
            float wv = slot[j * H + d];
            w_g[i] = wv;
            unsigned short hi = f2bf(wv);
            w_hi[i] = hi; w_lo[i] = f2bf(wv - bf2f(hi));
            float hv = ench[b * H + d];
            h_g[i] = hv;
            hi = f2bf(hv);
            h_hi[i] = hi; h_lo[i] = f2bf(hv - bf2f(hi));
        }
    }
}

// ---------------- GRU GEMMs: gi = w @ W_ih^T, gh = h @ W_hh^T (split-bf16, fp32-accurate) ----
#define GRU_APAD 520
__global__ __launch_bounds__(256) void k_gru_gemm(
    const unsigned short* __restrict__ w_hi, const unsigned short* __restrict__ w_lo,
    const unsigned short* __restrict__ h_hi, const unsigned short* __restrict__ h_lo,
    const unsigned short* __restrict__ wih_hi, const unsigned short* __restrict__ wih_lo,
    const unsigned short* __restrict__ whh_hi, const unsigned short* __restrict__ whh_lo,
    float* __restrict__ gi, float* __restrict__ gh)
{
    __shared__ unsigned short Ah[16 * GRU_APAD];
    __shared__ unsigned short Al[16 * GRU_APAD];
    int nch = blockIdx.x, mt = blockIdx.y, z = blockIdx.z;
    const unsigned short* Asrc_hi = z ? h_hi : w_hi;
    const unsigned short* Asrc_lo = z ? h_lo : w_lo;
    const unsigned short* Bhi = z ? whh_hi : wih_hi;
    const unsigned short* Blo = z ? whh_lo : wih_lo;
    float* outp = z ? gh : gi;
    int t = threadIdx.x;
    for (int i = t; i < 2048; i += 256) {
        int matl = i >> 10;
        int row = (i >> 6) & 15;
        int seg = i & 63;
        const unsigned short* src = (matl ? Asrc_lo : Asrc_hi) + (mt * 16 + row) * 512 + seg * 8;
        unsigned short* dst = (matl ? Al : Ah) + row * GRU_APAD + seg * 8;
        *(short8*)dst = *(const short8*)src;
    }
    __syncthreads();
    int wv = t >> 6, lane = t & 63;
    int col15 = lane & 15, quad = lane >> 4;
    f32x4 acc0 = {0.f, 0.f, 0.f, 0.f}, acc1 = {0.f, 0.f, 0.f, 0.f};
    int c0 = nch * 128 + wv * 32 + col15;
    int c1 = c0 + 16;
    const unsigned short* bhp0 = Bhi + c0 * 512 + quad * 8;
    const unsigned short* bhp1 = Bhi + c1 * 512 + quad * 8;
    const unsigned short* blp0 = Blo + c0 * 512 + quad * 8;
    const unsigned short* blp1 = Blo + c1 * 512 + quad * 8;
    const unsigned short* ahp = Ah + col15 * GRU_APAD + quad * 8;
    const unsigned short* alp = Al + col15 * GRU_APAD + quad * 8;
#pragma unroll
    for (int ks = 0; ks < 16; ks++) {
        int ko = ks * 32;
        short8 bh0 = *(const short8*)(bhp0 + ko);
        short8 bh1 = *(const short8*)(bhp1 + ko);
        short8 bl0 = *(const short8*)(blp0 + ko);
        short8 bl1 = *(const short8*)(blp1 + ko);
        short8 ah = *(const short8*)(ahp + ko);
        short8 al = *(const short8*)(alp + ko);
        acc0 = __builtin_amdgcn_mfma_f32_16x16x32_bf16(ah, bh0, acc0, 0, 0, 0);
        acc1 = __builtin_amdgcn_mfma_f32_16x16x32_bf16(ah, bh1, acc1, 0, 0, 0);
        acc0 = __builtin_amdgcn_mfma_f32_16x16x32_bf16(ah, bl0, acc0, 0, 0, 0);
        acc1 = __builtin_amdgcn_mfma_f32_16x16x32_bf16(ah, bl1, acc1, 0, 0, 0);
        acc0 = __builtin_amdgcn_mfma_f32_16x16x32_bf16(al, bh0, acc0, 0, 0, 0);
        acc1 = __builtin_amdgcn_mfma_f32_16x16x32_bf16(al, bh1, acc1, 0, 0, 0);
    }
#pragma unroll
    for (int r = 0; r < 4; r++) {
        int row = mt * 16 + quad * 4 + r;
        outp[row * 1536 + c0] = acc0[r];
        outp[row * 1536 + c1] = acc1[r];
    }
}

// --------- fused: GRU pointwise + attention scores + softmax + context + p_gen -------------
__global__ __launch_bounds__(256) void k_attention(
    const float* __restrict__ gi, const float* __restrict__ gh,
    const float* __restrict__ b_ih, const float* __restrict__ b_hh,
    float* __restrict__ h_g, unsigned short* __restrict__ h_hi, unsigned short* __restrict__ h_lo,
    const float* __restrict__ enc, const int* __restrict__ x,
    const float* __restrict__ w_g, const float* __restrict__ wgenW, const float* __restrict__ wgenb,
    float* __restrict__ attn_g, float* __restrict__ pgen_g,
    float* __restrict__ ctx0, int store_ctx,
    float* __restrict__ rowsum, unsigned long long* __restrict__ argpk)
{
    __shared__ float h_lds[512];
    __shared__ float sc[256];
    __shared__ float red[256];
    __shared__ float ctxp[4 * 512];
    int jb = blockIdx.x;
    int b = jb & 15;
    int t = threadIdx.x;
    if (t == 0) { rowsum[jb] = 0.f; argpk[jb] = 0ull; }   // zeroed for this step's vgemm
    // GRU pointwise (PyTorch gate order r,z,n)
    for (int d = t; d < 512; d += 256) {
        int base = jb * 1536;
        float ir = gi[base + d]        + b_ih[d];
        float iz = gi[base + 512 + d]  + b_ih[512 + d];
        float in = gi[base + 1024 + d] + b_ih[1024 + d];
        float hr = gh[base + d]        + b_hh[d];
        float hz = gh[base + 512 + d]  + b_hh[512 + d];
        float hn = gh[base + 1024 + d] + b_hh[1024 + d];
        float hold = h_g[jb * 512 + d];
        float r = 1.f / (1.f + expf(-(ir + hr)));
        float z = 1.f / (1.f + expf(-(iz + hz)));
        float n = tanhf(in + r * hn);
        float hnew = (1.f - z) * n + z * hold;
        h_lds[d] = hnew;
        h_g[jb * 512 + d] = hnew;
        unsigned short hi = f2bf(hnew);
        h_hi[jb * 512 + d] = hi;
        h_lo[jb * 512 + d] = f2bf(hnew - bf2f(hi));
    }
    __syncthreads();
    int wid = t >> 6, lane = t & 63;
    float hreg[8];
#pragma unroll
    for (int i = 0; i < 8; i++) hreg[i] = h_lds[lane * 8 + i];
    const float* encb = enc + (size_t)b * NS * H;
    for (int s = wid; s < NS; s += 4) {
        const float4* er = (const float4*)(encb + s * 512 + lane * 8);
        float4 e0 = er[0], e1 = er[1];
        float p = e0.x * hreg[0] + e0.y * hreg[1] + e0.z * hreg[2] + e0.w * hreg[3]
                + e1.x * hreg[4] + e1.y * hreg[5] + e1.z * hreg[6] + e1.w * hreg[7];
#pragma unroll
        for (int off = 32; off > 0; off >>= 1) p += __shfl_down(p, off);
        if (lane == 0) sc[s] = (x[b * NS + s] == 0) ? NEGV : p;
    }
    __syncthreads();
    // softmax over s
    red[t] = sc[t];
    __syncthreads();
    for (int sft = 128; sft > 0; sft >>= 1) { if (t < sft) red[t] = fmaxf(red[t], red[t + sft]); __syncthreads(); }
    float m = red[0];
    __syncthreads();
    float e = expf(sc[t] - m);
    red[t] = e;
    __syncthreads();
    for (int sft = 128; sft > 0; sft >>= 1) { if (t < sft) red[t] += red[t + sft]; __syncthreads(); }
    float inv = 1.f / red[0];
    float p_s = e * inv;
    sc[t] = p_s;
    attn_g[jb * NS + t] = p_s;
    __syncthreads();
    // context: wave `wid` covers s in [wid*64, wid*64+64), lane covers 8 dims
    {
        float cp[8] = {0.f,0.f,0.f,0.f,0.f,0.f,0.f,0.f};
        const float* encw = encb + lane * 8;
        for (int s = wid * 64; s < wid * 64 + 64; s++) {
            float ps = sc[s];
            const float4* er = (const float4*)(encw + s * 512);
            float4 e0 = er[0], e1 = er[1];
            cp[0] += ps * e0.x; cp[1] += ps * e0.y; cp[2] += ps * e0.z; cp[3] += ps * e0.w;
            cp[4] += ps * e1.x; cp[5] += ps * e1.y; cp[6] += ps * e1.z; cp[7] += ps * e1.w;
        }
        float* cw = ctxp + wid * 512 + lane * 8;
#pragma unroll
        for (int i = 0; i < 8; i++) cw[i] = cp[i];
    }
    __syncthreads();
    int d0 = 2 * t, d1 = 2 * t + 1;
    float c0 = ctxp[d0] + ctxp[512 + d0] + ctxp[1024 + d0] + ctxp[1536 + d0];
    float c1 = ctxp[d1] + ctxp[512 + d1] + ctxp[1024 + d1] + ctxp[1536 + d1];
    if (store_ctx) ((float2*)ctx0)[jb * 256 + t] = make_float2(c0, c1);
    float pg = wgenW[d0] * w_g[jb * 512 + d0] + wgenW[d1] * w_g[jb * 512 + d1]
             + wgenW[512 + d0] * h_lds[d0] + wgenW[512 + d1] * h_lds[d1]
             + wgenW[1024 + d0] * c0 + wgenW[1024 + d1] * c1;
    __syncthreads();
    red[t] = pg;
    __syncthreads();
    for (int sft = 128; sft > 0; sft >>= 1) { if (t < sft) red[t] += red[t + sft]; __syncthreads(); }
    if (t == 0) pgen_g[jb] = 1.f / (1.f + expf(-(red[0] + wgenb[0])));
}

// ------- vocab GEMM, latency-optimized: zero-LDS streaming K-loop, no barriers in main loop.
// A (h_hi, 160KB) read straight from L2 per-fragment; B (emb_bf) streamed from HBM/L3.
// 469 blocks x 4 waves = 1876 waves (~1.8/SIMD) vs old 240x4 (~0.94/SIMD); per-wave the
// unroll-4 window keeps ~44 independent 16B loads in flight -> latency hidden by ILP+TLP.
#define VBLK 64
#define LDSP 76        // 152B row stride: 4*38 words mod 32 = {0,24,16,8} -> quad rows bank-spread
__global__ __launch_bounds__(256) void k_vgemm(
    const unsigned short* __restrict__ h_hi, const unsigned short* __restrict__ emb_bf,
    unsigned short* __restrict__ E, float* __restrict__ rowsum,
    unsigned long long* __restrict__ argpk)
{
    __shared__ unsigned short A[160 * LDSP];   // output transpose buffer only (24.3 KB)
    int blk = blockIdx.x;
    int t = threadIdx.x;
    int wv = t >> 6, lane = t & 63, col15 = lane & 15, quad = lane >> 4;
    int v = blk * VBLK + wv * 16 + col15;
    int vc = min(v, V - 1);
    f32x4 acc[10];
#pragma unroll
    for (int m = 0; m < 10; m++) acc[m] = (f32x4){0.f, 0.f, 0.f, 0.f};
    const unsigned short* bp = emb_bf + (size_t)vc * 512 + quad * 8;
    const unsigned short* ap = h_hi + col15 * 512 + quad * 8;
#pragma unroll 4
    for (int ks = 0; ks < 16; ks++) {
        short8 b = *(const short8*)(bp + ks * 32);
#pragma unroll
        for (int m = 0; m < 10; m++) {
            short8 a = *(const short8*)(ap + m * 8192 + ks * 32);
            acc[m] = __builtin_amdgcn_mfma_f32_16x16x32_bf16(a, b, acc[m], 0, 0, 0);
        }
    }
    // exp + transpose into LDS (row-major per block: 160 x 64 bf16)
#pragma unroll
    for (int m = 0; m < 10; m++) {
#pragma unroll
        for (int r = 0; r < 4; r++) {
            int row = m * 16 + quad * 4 + r;
            float ev = (v < V) ? expf(acc[m][r]) : 0.f;
            A[row * LDSP + wv * 16 + col15] = f2bf(ev);
        }
    }
    __syncthreads();
    // per-row sum + max over this block's 64 cols
    if (t < 160) {
        float s = 0.f;
        unsigned long long key = 0ull;
#pragma unroll
        for (int seg = 0; seg < 8; seg++) {
            short8 ev = *(const short8*)(A + t * LDSP + seg * 8);
#pragma unroll
            for (int k = 0; k < 8; k++) {
                float f = bf2f((unsigned short)ev[k]);
                s += f;
                unsigned long long kk = packkey(f, blk * VBLK + seg * 8 + k);
                key = (kk > key) ? kk : key;
            }
        }
        atomicAdd(rowsum + t, s);
        atomicMax(argpk + t, key);
    }
    // coalesced E store: 8 lanes per row (short8 each = 128B/row), 32 rows in flight, 5 iters
    {
        int rsub = t >> 3, seg = t & 7;
        for (int it = 0; it < 5; it++) {
            int row = it * 32 + rsub;
            short8 ev = *(const short8*)(A + row * LDSP + seg * 8);
            *(short8*)(E + (size_t)row * EV + blk * VBLK + seg * 8) = ev;
        }
    }
}

// ------- finalize: scale+write dense (coalesced), scatter, argmax, w_next, gates@t0 -------
__global__ __launch_bounds__(256) void k_finalize(
    const unsigned short* __restrict__ E, const float* __restrict__ pgen_g,
    const float* __restrict__ rowsum, const unsigned long long* __restrict__ argpk,
    const float* __restrict__ attn_g, const int* __restrict__ x,
    const float* __restrict__ emb, float* __restrict__ out,
    float* __restrict__ w_g, unsigned short* __restrict__ w_hi, unsigned short* __restrict__ w_lo,
    const float* __restrict__ ctx0, const float* __restrict__ aW, const float* __restrict__ ab,
    int tstep)
{
    __shared__ float bvs[256];
    __shared__ int bis[256];
    __shared__ float red[256];
    int jb = blockIdx.x, t = threadIdx.x;
    int j = jb >> 4, b = jb & 15;
    float inv = 1.f / rowsum[jb];
    float pgen = pgen_g[jb];
    float scale = pgen * inv;
    const unsigned short* Er = E + (size_t)jb * EV;
    size_t outbase = (size_t)640 + ((size_t)(b * NJ + j) * NT + tstep) * V;
    float* op = out + outbase;
    // dense write: short8 loads, lane-consecutive float4 stores
    for (int c = 0; c < 14; c++) {
        int vv = c * 2048 + t * 8;
        short8 e = *(const short8*)(Er + vv);
        float4 p0 = make_float4(bf2f((unsigned short)e[0]) * scale, bf2f((unsigned short)e[1]) * scale,
                                bf2f((unsigned short)e[2]) * scale, bf2f((unsigned short)e[3]) * scale);
        float4 p1 = make_float4(bf2f((unsigned short)e[4]) * scale, bf2f((unsigned short)e[5]) * scale,
                                bf2f((unsigned short)e[6]) * scale, bf2f((unsigned short)e[7]) * scale);
        *(float4*)(op + vv) = p0;
        *(float4*)(op + vv + 4) = p1;
    }
    if (t < 166) {
        int vv = 28672 + t * 8;
        short8 e = *(const short8*)(Er + vv);
        float4 p0 = make_float4(bf2f((unsigned short)e[0]) * scale, bf2f((unsigned short)e[1]) * scale,
                                bf2f((unsigned short)e[2]) * scale, bf2f((unsigned short)e[3]) * scale);
        float4 p1 = make_float4(bf2f((unsigned short)e[4]) * scale, bf2f((unsigned short)e[5]) * scale,
                                bf2f((unsigned short)e[6]) * scale, bf2f((unsigned short)e[7]) * scale);
        *(float4*)(op + vv) = p0;
        *(float4*)(op + vv + 4) = p1;
    }
    __syncthreads();   // dense stores drained before scatter atomics
    // pointer scatter + candidate tracking
    float best; int besti;
    {
        int vv = x[b * NS + t];
        float a = (1.f - pgen) * attn_g[jb * NS + t];
        float old = atomicAdd(&op[vv], a);
        best = old + a;    // last adder to each vv sees the true final value
        besti = vv;
    }
    bvs[t] = best; bis[t] = besti;
    __syncthreads();
    for (int sft = 128; sft > 0; sft >>= 1) {
        if (t < sft) {
            if (bvs[t + sft] > bvs[t] || (bvs[t + sft] == bvs[t] && bis[t + sft] < bis[t])) {
                bvs[t] = bvs[t + sft]; bis[t] = bis[t + sft];
            }
        }
        __syncthreads();
    }
    // combine with dense argmax from vgemm
    int widx;
    {
        unsigned long long key = argpk[jb];
        union { unsigned int u; float f; } c; c.u = (unsigned int)(key >> 32);
        float db = c.f * scale;
        int di = 0x7FFFFFFF - (int)(key & 0xFFFFFFFFu);
        float sb = bvs[0]; int si = bis[0];
        widx = (sb > db || (sb == db && si < di)) ? si : di;
    }
    // w_next gather + bf16 split
    for (int d = t; d < 512; d += 256) {
        float val = emb[(size_t)widx * 512 + d];
        w_g[jb * 512 + d] = val;
        unsigned short hi = f2bf(val);
        w_hi[jb * 512 + d] = hi;
        w_lo[jb * 512 + d] = f2bf(val - bf2f(hi));
    }
    // gate head (uses step-0 context)
    if (tstep == 0) {
        float part[4] = {0.f, 0.f, 0.f, 0.f};
        for (int d = t; d < 512; d += 256) {
            float c = ctx0[jb * 512 + d];
#pragma unroll
            for (int o = 0; o < 4; o++) part[o] += c * aW[o * 512 + d];
        }
        for (int o = 0; o < 4; o++) {
            __syncthreads();
            red[t] = part[o];
            __syncthreads();
            for (int sft = 128; sft > 0; sft >>= 1) { if (t < sft) red[t] += red[t + sft]; __syncthreads(); }
            if (t == 0) out[(b * NJ + j) * NOPS + o] = red[0] + ab[o];
        }
    }
}

extern "C" void kernel_launch(void* const* d_in, const int* in_sizes, int n_in,
                              void* d_out, int out_size, void* d_ws, size_t ws_size,
                              hipStream_t stream) {
    const int*   x     = (const int*)d_in[0];
    const float* enc   = (const float*)d_in[1];
    const float* ench  = (const float*)d_in[2];
    const float* embW  = (const float*)d_in[4];
    const float* slot  = (const float*)d_in[5];
    const float* Wih   = (const float*)d_in[6];
    const float* Whh   = (const float*)d_in[7];
    const float* bih   = (const float*)d_in[8];
    const float* bhh   = (const float*)d_in[9];
    const float* wgenW = (const float*)d_in[10];
    const float* wgenb = (const float*)d_in[11];
    const float* aW    = (const float*)d_in[12];
    const float* ab    = (const float*)d_in[13];
    float* out = (float*)d_out;

    char* ws = (char*)d_ws;
    size_t off = 0;
    auto carve = [&](size_t bytes) { char* p = ws + off; off += (bytes + 255) & ~(size_t)255; return p; };
    unsigned short* emb_bf = (unsigned short*)carve((size_t)V * H * 2);
    unsigned short* wih_hi = (unsigned short*)carve(786432 * 2);
    unsigned short* wih_lo = (unsigned short*)carve(786432 * 2);
    unsigned short* whh_hi = (unsigned short*)carve(786432 * 2);
    unsigned short* whh_lo = (unsigned short*)carve(786432 * 2);
    float* w_f32 = (float*)carve(NR * H * 4);
    float* h_f32 = (float*)carve(NR * H * 4);
    float* ctx0  = (float*)carve(NR * H * 4);
    unsigned short* w_hi = (unsigned short*)carve(NR * H * 2);
    unsigned short* w_lo = (unsigned short*)carve(NR * H * 2);
    unsigned short* h_hi = (unsigned short*)carve(NR * H * 2);
    unsigned short* h_lo = (unsigned short*)carve(NR * H * 2);
    float* gi   = (float*)carve(NR * 1536 * 4);
    float* gh   = (float*)carve(NR * 1536 * 4);
    float* attn = (float*)carve(NR * NS * 4);
    float* pgen = (float*)carve(NR * 4);
    float* rowsum = (float*)carve(NR * 4);
    unsigned long long* argpk = (unsigned long long*)carve(NR * 8);
    unsigned short* E = (unsigned short*)carve((size_t)NR * EV * 2);

    k_setup_emb<<<7500, 256, 0, stream>>>(embW, emb_bf, (V * H) / 8);
    k_setup_small<<<3392, 256, 0, stream>>>(Wih, Whh, wih_hi, wih_lo, whh_hi, whh_lo,
                                            slot, ench, w_f32, w_hi, w_lo, h_f32, h_hi, h_lo);
    for (int t = 0; t < NT; t++) {
        k_gru_gemm<<<dim3(12, 10, 2), 256, 0, stream>>>(w_hi, w_lo, h_hi, h_lo,
                                                        wih_hi, wih_lo, whh_hi, whh_lo, gi, gh);
        k_attention<<<NR, 256, 0, stream>>>(gi, gh, bih, bhh, h_f32, h_hi, h_lo, enc, x,
                                            w_f32, wgenW, wgenb, attn, pgen, ctx0, t == 0 ? 1 : 0,
                                            rowsum, argpk);
        k_vgemm<<<469, 256, 0, stream>>>(h_hi, emb_bf, E, rowsum, argpk);
        k_finalize<<<NR, 256, 0, stream>>>(E, pgen, rowsum, argpk, attn, x, embW, out,
                                           w_f32, w_hi, w_lo, ctx0, aW, ab, t);
    }
}

// Round 4
// 1113.449 us; speedup vs baseline: 1.1331x; 1.1331x over previous
//
#include <hip/hip_runtime.h>
#include <math.h>

#define V 30000
#define H 512
#define NB 16
#define NS 256
#define NJ 10
#define NT 8
#define NOPS 4
#define NR 160          // NJ*NB rows
#define EV 30720        // padded E row stride
#define NEGV -1e9f
#define NTILES 1875     // V/16 vocab n-tiles

typedef __attribute__((ext_vector_type(8))) short short8;
typedef __attribute__((ext_vector_type(4))) short short4v;
typedef __attribute__((ext_vector_type(4))) float f32x4;

__device__ inline float bf2f(unsigned short s) {
    union { unsigned int u; float f; } c; c.u = ((unsigned int)s) << 16;
    return c.f;
}
__device__ inline unsigned short f2bf(float f) {
    union { float f; unsigned int u; } c; c.f = f;
    unsigned int u = c.u;
    u += 0x7fffu + ((u >> 16) & 1u);   // RNE
    return (unsigned short)(u >> 16);
}
__device__ inline unsigned long long packkey(float f, int v) {
    union { float f; unsigned int u; } c; c.f = f;
    return ((unsigned long long)c.u << 32) | (unsigned int)(0x7FFFFFFF - v);
}

// ---------------- setup: pack emb_W into MFMA B-fragment order (bf16) ----------------
// emb_pk[((nt*16 + ks)*64 + lane)*8 + e] = emb[nt*16 + (lane&15)][ks*32 + (lane>>4)*8 + e]
// so a wave's B-fragment load for (nt, ks) is 64 consecutive short8s = 1KB fully coalesced.
__global__ __launch_bounds__(256) void k_setup_pack(const float* __restrict__ emb,
                                                    unsigned short* __restrict__ emb_pk) {
    __shared__ unsigned short L[16 * 512];
    int nt = blockIdx.x;          // 0..1874
    int t = threadIdx.x;
#pragma unroll
    for (int i = 0; i < 4; i++) {
        int o = i * 2048 + t * 8;
        int row = o >> 9, k = o & 511;
        const float4* src = (const float4*)(emb + (size_t)(nt * 16 + row) * 512 + k);
        float4 a = src[0], b = src[1];
        short8 v;
        v[0] = (short)f2bf(a.x); v[1] = (short)f2bf(a.y); v[2] = (short)f2bf(a.z); v[3] = (short)f2bf(a.w);
        v[4] = (short)f2bf(b.x); v[5] = (short)f2bf(b.y); v[6] = (short)f2bf(b.z); v[7] = (short)f2bf(b.w);
        *(short8*)(L + o) = v;
    }
    __syncthreads();
#pragma unroll
    for (int i = 0; i < 4; i++) {
        int idx = i * 256 + t;
        int ks = idx >> 6, l = idx & 63;
        int col15 = l & 15, quad = l >> 4;
        short8 v = *(const short8*)(L + col15 * 512 + ks * 32 + quad * 8);
        *(short8*)(emb_pk + ((size_t)(nt * 16 + ks) * 64 + l) * 8) = v;
    }
}

// ---------------- setup: W splits + initial w/h state (+ h_pk fragment layout) ----------------
__global__ void k_setup_small(const float* __restrict__ Wih, const float* __restrict__ Whh,
    unsigned short* wih_hi, unsigned short* wih_lo, unsigned short* whh_hi, unsigned short* whh_lo,
    const float* __restrict__ slot, const float* __restrict__ ench,
    float* w_g, unsigned short* w_hi, unsigned short* w_lo,
    float* h_g, unsigned short* h_hi, unsigned short* h_lo, unsigned short* h_pk)
{
    int gid = blockIdx.x * 256 + threadIdx.x;
    if (gid < 786432) {
        float v1 = Wih[gid];
        unsigned short hi = f2bf(v1);
        wih_hi[gid] = hi; wih_lo[gid] = f2bf(v1 - bf2f(hi));
        float v2 = Whh[gid];
        hi = f2bf(v2);
        whh_hi[gid] = hi; whh_lo[gid] = f2bf(v2 - bf2f(hi));
    } else {
        int i = gid - 786432;
        if (i < NR * H) {
            int jb = i >> 9, d = i & 511;
            int j = jb >> 4, b = jb & 15;
            float wv = slot[j * H + d];
            w_g[i] = wv;
            unsigned short hi = f2bf(wv);
            w_hi[i] = hi; w_lo[i] = f2bf(wv - bf2f(hi));
            float hv = ench[b * H + d];
            h_g[i] = hv;
            hi = f2bf(hv);
            h_hi[i] = hi; h_lo[i] = f2bf(hv - bf2f(hi));
            int ks = d >> 5, quad = (d >> 3) & 3, e = d & 7;
            h_pk[(((jb >> 4) * 16 + ks) * 64 + quad * 16 + (jb & 15)) * 8 + e] = hi;
        }
    }
}

// ---------------- GRU GEMMs: gi = w @ W_ih^T, gh = h @ W_hh^T (split-bf16, fp32-accurate) ----
#define GRU_APAD 520
__global__ __launch_bounds__(256) void k_gru_gemm(
    const unsigned short* __restrict__ w_hi, const unsigned short* __restrict__ w_lo,
    const unsigned short* __restrict__ h_hi, const unsigned short* __restrict__ h_lo,
    const unsigned short* __restrict__ wih_hi, const unsigned short* __restrict__ wih_lo,
    const unsigned short* __restrict__ whh_hi, const unsigned short* __restrict__ whh_lo,
    float* __restrict__ gi, float* __restrict__ gh)
{
    __shared__ unsigned short Ah[16 * GRU_APAD];
    __shared__ unsigned short Al[16 * GRU_APAD];
    int nch = blockIdx.x, mt = blockIdx.y, z = blockIdx.z;
    const unsigned short* Asrc_hi = z ? h_hi : w_hi;
    const unsigned short* Asrc_lo = z ? h_lo : w_lo;
    const unsigned short* Bhi = z ? whh_hi : wih_hi;
    const unsigned short* Blo = z ? whh_lo : wih_lo;
    float* outp = z ? gh : gi;
    int t = threadIdx.x;
    for (int i = t; i < 2048; i += 256) {
        int matl = i >> 10;
        int row = (i >> 6) & 15;
        int seg = i & 63;
        const unsigned short* src = (matl ? Asrc_lo : Asrc_hi) + (mt * 16 + row) * 512 + seg * 8;
        unsigned short* dst = (matl ? Al : Ah) + row * GRU_APAD + seg * 8;
        *(short8*)dst = *(const short8*)src;
    }
    __syncthreads();
    int wv = t >> 6, lane = t & 63;
    int col15 = lane & 15, quad = lane >> 4;
    f32x4 acc0 = {0.f, 0.f, 0.f, 0.f}, acc1 = {0.f, 0.f, 0.f, 0.f};
    int c0 = nch * 128 + wv * 32 + col15;
    int c1 = c0 + 16;
    const unsigned short* bhp0 = Bhi + c0 * 512 + quad * 8;
    const unsigned short* bhp1 = Bhi + c1 * 512 + quad * 8;
    const unsigned short* blp0 = Blo + c0 * 512 + quad * 8;
    const unsigned short* blp1 = Blo + c1 * 512 + quad * 8;
    const unsigned short* ahp = Ah + col15 * GRU_APAD + quad * 8;
    const unsigned short* alp = Al + col15 * GRU_APAD + quad * 8;
#pragma unroll
    for (int ks = 0; ks < 16; ks++) {
        int ko = ks * 32;
        short8 bh0 = *(const short8*)(bhp0 + ko);
        short8 bh1 = *(const short8*)(bhp1 + ko);
        short8 bl0 = *(const short8*)(blp0 + ko);
        short8 bl1 = *(const short8*)(blp1 + ko);
        short8 ah = *(const short8*)(ahp + ko);
        short8 al = *(const short8*)(alp + ko);
        acc0 = __builtin_amdgcn_mfma_f32_16x16x32_bf16(ah, bh0, acc0, 0, 0, 0);
        acc1 = __builtin_amdgcn_mfma_f32_16x16x32_bf16(ah, bh1, acc1, 0, 0, 0);
        acc0 = __builtin_amdgcn_mfma_f32_16x16x32_bf16(ah, bl0, acc0, 0, 0, 0);
        acc1 = __builtin_amdgcn_mfma_f32_16x16x32_bf16(ah, bl1, acc1, 0, 0, 0);
        acc0 = __builtin_amdgcn_mfma_f32_16x16x32_bf16(al, bh0, acc0, 0, 0, 0);
        acc1 = __builtin_amdgcn_mfma_f32_16x16x32_bf16(al, bh1, acc1, 0, 0, 0);
    }
#pragma unroll
    for (int r = 0; r < 4; r++) {
        int row = mt * 16 + quad * 4 + r;
        outp[row * 1536 + c0] = acc0[r];
        outp[row * 1536 + c1] = acc1[r];
    }
}

// --------- fused: GRU pointwise + attention scores + softmax + context + p_gen -------------
__global__ __launch_bounds__(256) void k_attention(
    const float* __restrict__ gi, const float* __restrict__ gh,
    const float* __restrict__ b_ih, const float* __restrict__ b_hh,
    float* __restrict__ h_g, unsigned short* __restrict__ h_hi, unsigned short* __restrict__ h_lo,
    unsigned short* __restrict__ h_pk,
    const float* __restrict__ enc, const int* __restrict__ x,
    const float* __restrict__ w_g, const float* __restrict__ wgenW, const float* __restrict__ wgenb,
    float* __restrict__ attn_g, float* __restrict__ pgen_g,
    float* __restrict__ ctx0, int store_ctx,
    float* __restrict__ rowsum, unsigned long long* __restrict__ argpk)
{
    __shared__ float h_lds[512];
    __shared__ float sc[256];
    __shared__ float red[256];
    __shared__ float ctxp[4 * 512];
    int jb = blockIdx.x;
    int b = jb & 15;
    int t = threadIdx.x;
    if (t == 0) { rowsum[jb] = 0.f; argpk[jb] = 0ull; }   // zeroed for this step's vgemm
    int m_pk = jb >> 4, c_pk = jb & 15;
    // GRU pointwise (PyTorch gate order r,z,n)
    for (int d = t; d < 512; d += 256) {
        int base = jb * 1536;
        float ir = gi[base + d]        + b_ih[d];
        float iz = gi[base + 512 + d]  + b_ih[512 + d];
        float in = gi[base + 1024 + d] + b_ih[1024 + d];
        float hr = gh[base + d]        + b_hh[d];
        float hz = gh[base + 512 + d]  + b_hh[512 + d];
        float hn = gh[base + 1024 + d] + b_hh[1024 + d];
        float hold = h_g[jb * 512 + d];
        float r = 1.f / (1.f + expf(-(ir + hr)));
        float z = 1.f / (1.f + expf(-(iz + hz)));
        float n = tanhf(in + r * hn);
        float hnew = (1.f - z) * n + z * hold;
        h_lds[d] = hnew;
        h_g[jb * 512 + d] = hnew;
        unsigned short hi = f2bf(hnew);
        h_hi[jb * 512 + d] = hi;
        h_lo[jb * 512 + d] = f2bf(hnew - bf2f(hi));
        int ks = d >> 5, quad = (d >> 3) & 3, e = d & 7;
        h_pk[((m_pk * 16 + ks) * 64 + quad * 16 + c_pk) * 8 + e] = hi;
    }
    __syncthreads();
    int wid = t >> 6, lane = t & 63;
    float hreg[8];
#pragma unroll
    for (int i = 0; i < 8; i++) hreg[i] = h_lds[lane * 8 + i];
    const float* encb = enc + (size_t)b * NS * H;
    for (int s = wid; s < NS; s += 4) {
        const float4* er = (const float4*)(encb + s * 512 + lane * 8);
        float4 e0 = er[0], e1 = er[1];
        float p = e0.x * hreg[0] + e0.y * hreg[1] + e0.z * hreg[2] + e0.w * hreg[3]
                + e1.x * hreg[4] + e1.y * hreg[5] + e1.z * hreg[6] + e1.w * hreg[7];
#pragma unroll
        for (int off = 32; off > 0; off >>= 1) p += __shfl_down(p, off);
        if (lane == 0) sc[s] = (x[b * NS + s] == 0) ? NEGV : p;
    }
    __syncthreads();
    // softmax over s
    red[t] = sc[t];
    __syncthreads();
    for (int sft = 128; sft > 0; sft >>= 1) { if (t < sft) red[t] = fmaxf(red[t], red[t + sft]); __syncthreads(); }
    float m = red[0];
    __syncthreads();
    float e = expf(sc[t] - m);
    red[t] = e;
    __syncthreads();
    for (int sft = 128; sft > 0; sft >>= 1) { if (t < sft) red[t] += red[t + sft]; __syncthreads(); }
    float inv = 1.f / red[0];
    float p_s = e * inv;
    sc[t] = p_s;
    attn_g[jb * NS + t] = p_s;
    __syncthreads();
    // context: wave `wid` covers s in [wid*64, wid*64+64), lane covers 8 dims
    {
        float cp[8] = {0.f,0.f,0.f,0.f,0.f,0.f,0.f,0.f};
        const float* encw = encb + lane * 8;
        for (int s = wid * 64; s < wid * 64 + 64; s++) {
            float ps = sc[s];
            const float4* er = (const float4*)(encw + s * 512);
            float4 e0 = er[0], e1 = er[1];
            cp[0] += ps * e0.x; cp[1] += ps * e0.y; cp[2] += ps * e0.z; cp[3] += ps * e0.w;
            cp[4] += ps * e1.x; cp[5] += ps * e1.y; cp[6] += ps * e1.z; cp[7] += ps * e1.w;
        }
        float* cw = ctxp + wid * 512 + lane * 8;
#pragma unroll
        for (int i = 0; i < 8; i++) cw[i] = cp[i];
    }
    __syncthreads();
    int d0 = 2 * t, d1 = 2 * t + 1;
    float c0 = ctxp[d0] + ctxp[512 + d0] + ctxp[1024 + d0] + ctxp[1536 + d0];
    float c1 = ctxp[d1] + ctxp[512 + d1] + ctxp[1024 + d1] + ctxp[1536 + d1];
    if (store_ctx) ((float2*)ctx0)[jb * 256 + t] = make_float2(c0, c1);
    float pg = wgenW[d0] * w_g[jb * 512 + d0] + wgenW[d1] * w_g[jb * 512 + d1]
             + wgenW[512 + d0] * h_lds[d0] + wgenW[512 + d1] * h_lds[d1]
             + wgenW[1024 + d0] * c0 + wgenW[1024 + d1] * c1;
    __syncthreads();
    red[t] = pg;
    __syncthreads();
    for (int sft = 128; sft > 0; sft >>= 1) { if (t < sft) red[t] += red[t + sft]; __syncthreads(); }
    if (t == 0) pgen_g[jb] = 1.f / (1.f + expf(-(red[0] + wgenb[0])));
}

// ------- vocab GEMM: both operands in fragment-packed layout => every global load is a
// fully-coalesced 1KB wave read (no cache-line splits). A chunk (40KB) staged in LDS per
// K=128 chunk; B read directly from emb_pk. 235 blocks x 128 cols.
#define VPAD 136
__global__ __launch_bounds__(256) void k_vgemm(
    const unsigned short* __restrict__ h_pk, const unsigned short* __restrict__ emb_pk,
    unsigned short* __restrict__ E, float* __restrict__ rowsum,
    unsigned long long* __restrict__ argpk)
{
    __shared__ unsigned short A[160 * VPAD];   // 43520B; first 40960B reused as A-chunk stage
    int blk = blockIdx.x;
    int t = threadIdx.x;
    int wv = t >> 6, lane = t & 63, col15 = lane & 15, quad = lane >> 4;
    f32x4 acc[10][2];
#pragma unroll
    for (int m = 0; m < 10; m++) {
        acc[m][0] = (f32x4){0.f, 0.f, 0.f, 0.f};
        acc[m][1] = (f32x4){0.f, 0.f, 0.f, 0.f};
    }
    int nt0 = blk * 8 + wv * 2;
    int nt0c = min(nt0, NTILES - 1);
    int nt1c = min(nt0 + 1, NTILES - 1);
    for (int kc = 0; kc < 4; kc++) {
        __syncthreads();
        // stage A chunk: h_pk fragments for ks in [kc*4, kc*4+4), all 10 m-tiles (coalesced)
#pragma unroll
        for (int i = 0; i < 10; i++) {
            int o = i * 2048 + t * 8;          // element offset in 20480-element chunk
            int m = o >> 11, rem = o & 2047;
            *(short8*)(A + m * 2048 + rem) =
                *(const short8*)(h_pk + (size_t)(m * 16 + kc * 4) * 512 + rem);
        }
        __syncthreads();
#pragma unroll
        for (int q = 0; q < 4; q++) {
            int ksg = kc * 4 + q;
            short8 b0 = *(const short8*)(emb_pk + ((size_t)(nt0c * 16 + ksg) * 64 + lane) * 8);
            short8 b1 = *(const short8*)(emb_pk + ((size_t)(nt1c * 16 + ksg) * 64 + lane) * 8);
#pragma unroll
            for (int m = 0; m < 10; m++) {
                short8 a = *(const short8*)(A + m * 2048 + q * 512 + lane * 8);
                acc[m][0] = __builtin_amdgcn_mfma_f32_16x16x32_bf16(a, b0, acc[m][0], 0, 0, 0);
                acc[m][1] = __builtin_amdgcn_mfma_f32_16x16x32_bf16(a, b1, acc[m][1], 0, 0, 0);
            }
        }
    }
    __syncthreads();   // all LDS A reads done; reuse as transpose buffer
    // exp + transpose into LDS: A[row * VPAD + col_local] (bf16)
#pragma unroll
    for (int m = 0; m < 10; m++) {
#pragma unroll
        for (int tile = 0; tile < 2; tile++) {
            int cl = wv * 32 + tile * 16 + col15;
            int vv = blk * 128 + cl;
#pragma unroll
            for (int r = 0; r < 4; r++) {
                int row = m * 16 + quad * 4 + r;
                float ev = (vv < V) ? expf(acc[m][tile][r]) : 0.f;
                A[row * VPAD + cl] = f2bf(ev);
            }
        }
    }
    __syncthreads();
    // per-row sum + max over this block's 128 cols
    if (t < 160) {
        float s = 0.f;
        unsigned long long key = 0ull;
#pragma unroll
        for (int seg = 0; seg < 16; seg++) {
            short8 ev = *(const short8*)(A + t * VPAD + seg * 8);
#pragma unroll
            for (int k = 0; k < 8; k++) {
                float f = bf2f((unsigned short)ev[k]);
                s += f;
                unsigned long long kk = packkey(f, blk * 128 + seg * 8 + k);
                key = (kk > key) ? kk : key;
            }
        }
        atomicAdd(rowsum + t, s);
        atomicMax(argpk + t, key);
    }
    // coalesced E store: 16 lanes per row (short8 each), 16 rows in flight, 10 iters
    {
        int rsub = t >> 4, seg = t & 15;
        for (int it = 0; it < 10; it++) {
            int row = it * 16 + rsub;
            short8 ev = *(const short8*)(A + row * VPAD + seg * 8);
            *(short8*)(E + (size_t)row * EV + blk * 128 + seg * 8) = ev;
        }
    }
}

// ------- finalize: scale+write dense (coalesced), scatter, argmax, w_next, gates@t0 -------
__global__ __launch_bounds__(256) void k_finalize(
    const unsigned short* __restrict__ E, const float* __restrict__ pgen_g,
    const float* __restrict__ rowsum, const unsigned long long* __restrict__ argpk,
    const float* __restrict__ attn_g, const int* __restrict__ x,
    const float* __restrict__ emb, float* __restrict__ out,
    float* __restrict__ w_g, unsigned short* __restrict__ w_hi, unsigned short* __restrict__ w_lo,
    const float* __restrict__ ctx0, const float* __restrict__ aW, const float* __restrict__ ab,
    int tstep)
{
    __shared__ float bvs[256];
    __shared__ int bis[256];
    __shared__ float red[256];
    int jb = blockIdx.x, t = threadIdx.x;
    int j = jb >> 4, b = jb & 15;
    float inv = 1.f / rowsum[jb];
    float pgen = pgen_g[jb];
    float scale = pgen * inv;
    const unsigned short* Er = E + (size_t)jb * EV;
    size_t outbase = (size_t)640 + ((size_t)(b * NJ + j) * NT + tstep) * V;
    float* op = out + outbase;
    // dense write: short8 loads, lane-consecutive float4 stores
    for (int c = 0; c < 14; c++) {
        int vv = c * 2048 + t * 8;
        short8 e = *(const short8*)(Er + vv);
        float4 p0 = make_float4(bf2f((unsigned short)e[0]) * scale, bf2f((unsigned short)e[1]) * scale,
                                bf2f((unsigned short)e[2]) * scale, bf2f((unsigned short)e[3]) * scale);
        float4 p1 = make_float4(bf2f((unsigned short)e[4]) * scale, bf2f((unsigned short)e[5]) * scale,
                                bf2f((unsigned short)e[6]) * scale, bf2f((unsigned short)e[7]) * scale);
        *(float4*)(op + vv) = p0;
        *(float4*)(op + vv + 4) = p1;
    }
    if (t < 166) {
        int vv = 28672 + t * 8;
        short8 e = *(const short8*)(Er + vv);
        float4 p0 = make_float4(bf2f((unsigned short)e[0]) * scale, bf2f((unsigned short)e[1]) * scale,
                                bf2f((unsigned short)e[2]) * scale, bf2f((unsigned short)e[3]) * scale);
        float4 p1 = make_float4(bf2f((unsigned short)e[4]) * scale, bf2f((unsigned short)e[5]) * scale,
                                bf2f((unsigned short)e[6]) * scale, bf2f((unsigned short)e[7]) * scale);
        *(float4*)(op + vv) = p0;
        *(float4*)(op + vv + 4) = p1;
    }
    __syncthreads();   // dense stores drained before scatter atomics
    // pointer scatter + candidate tracking
    float best; int besti;
    {
        int vv = x[b * NS + t];
        float a = (1.f - pgen) * attn_g[jb * NS + t];
        float old = atomicAdd(&op[vv], a);
        best = old + a;    // last adder to each vv sees the true final value
        besti = vv;
    }
    bvs[t] = best; bis[t] = besti;
    __syncthreads();
    for (int sft = 128; sft > 0; sft >>= 1) {
        if (t < sft) {
            if (bvs[t + sft] > bvs[t] || (bvs[t + sft] == bvs[t] && bis[t + sft] < bis[t])) {
                bvs[t] = bvs[t + sft]; bis[t] = bis[t + sft];
            }
        }
        __syncthreads();
    }
    // combine with dense argmax from vgemm
    int widx;
    {
        unsigned long long key = argpk[jb];
        union { unsigned int u; float f; } c; c.u = (unsigned int)(key >> 32);
        float db = c.f * scale;
        int di = 0x7FFFFFFF - (int)(key & 0xFFFFFFFFu);
        float sb = bvs[0]; int si = bis[0];
        widx = (sb > db || (sb == db && si < di)) ? si : di;
    }
    // w_next gather + bf16 split
    for (int d = t; d < 512; d += 256) {
        float val = emb[(size_t)widx * 512 + d];
        w_g[jb * 512 + d] = val;
        unsigned short hi = f2bf(val);
        w_hi[jb * 512 + d] = hi;
        w_lo[jb * 512 + d] = f2bf(val - bf2f(hi));
    }
    // gate head (uses step-0 context)
    if (tstep == 0) {
        float part[4] = {0.f, 0.f, 0.f, 0.f};
        for (int d = t; d < 512; d += 256) {
            float c = ctx0[jb * 512 + d];
#pragma unroll
            for (int o = 0; o < 4; o++) part[o] += c * aW[o * 512 + d];
        }
        for (int o = 0; o < 4; o++) {
            __syncthreads();
            red[t] = part[o];
            __syncthreads();
            for (int sft = 128; sft > 0; sft >>= 1) { if (t < sft) red[t] += red[t + sft]; __syncthreads(); }
            if (t == 0) out[(b * NJ + j) * NOPS + o] = red[0] + ab[o];
        }
    }
}

extern "C" void kernel_launch(void* const* d_in, const int* in_sizes, int n_in,
                              void* d_out, int out_size, void* d_ws, size_t ws_size,
                              hipStream_t stream) {
    const int*   x     = (const int*)d_in[0];
    const float* enc   = (const float*)d_in[1];
    const float* ench  = (const float*)d_in[2];
    const float* embW  = (const float*)d_in[4];
    const float* slot  = (const float*)d_in[5];
    const float* Wih   = (const float*)d_in[6];
    const float* Whh   = (const float*)d_in[7];
    const float* bih   = (const float*)d_in[8];
    const float* bhh   = (const float*)d_in[9];
    const float* wgenW = (const float*)d_in[10];
    const float* wgenb = (const float*)d_in[11];
    const float* aW    = (const float*)d_in[12];
    const float* ab    = (const float*)d_in[13];
    float* out = (float*)d_out;

    char* ws = (char*)d_ws;
    size_t off = 0;
    auto carve = [&](size_t bytes) { char* p = ws + off; off += (bytes + 255) & ~(size_t)255; return p; };
    unsigned short* emb_pk = (unsigned short*)carve((size_t)V * H * 2);
    unsigned short* wih_hi = (unsigned short*)carve(786432 * 2);
    unsigned short* wih_lo = (unsigned short*)carve(786432 * 2);
    unsigned short* whh_hi = (unsigned short*)carve(786432 * 2);
    unsigned short* whh_lo = (unsigned short*)carve(786432 * 2);
    float* w_f32 = (float*)carve(NR * H * 4);
    float* h_f32 = (float*)carve(NR * H * 4);
    float* ctx0  = (float*)carve(NR * H * 4);
    unsigned short* w_hi = (unsigned short*)carve(NR * H * 2);
    unsigned short* w_lo = (unsigned short*)carve(NR * H * 2);
    unsigned short* h_hi = (unsigned short*)carve(NR * H * 2);
    unsigned short* h_lo = (unsigned short*)carve(NR * H * 2);
    unsigned short* h_pk = (unsigned short*)carve(NR * H * 2);
    float* gi   = (float*)carve(NR * 1536 * 4);
    float* gh   = (float*)carve(NR * 1536 * 4);
    float* attn = (float*)carve(NR * NS * 4);
    float* pgen = (float*)carve(NR * 4);
    float* rowsum = (float*)carve(NR * 4);
    unsigned long long* argpk = (unsigned long long*)carve(NR * 8);
    unsigned short* E = (unsigned short*)carve((size_t)NR * EV * 2);

    k_setup_pack<<<NTILES, 256, 0, stream>>>(embW, emb_pk);
    k_setup_small<<<3392, 256, 0, stream>>>(Wih, Whh, wih_hi, wih_lo, whh_hi, whh_lo,
                                            slot, ench, w_f32, w_hi, w_lo, h_f32, h_hi, h_lo, h_pk);
    for (int t = 0; t < NT; t++) {
        k_gru_gemm<<<dim3(12, 10, 2), 256, 0, stream>>>(w_hi, w_lo, h_hi, h_lo,
                                                        wih_hi, wih_lo, whh_hi, whh_lo, gi, gh);
        k_attention<<<NR, 256, 0, stream>>>(gi, gh, bih, bhh, h_f32, h_hi, h_lo, h_pk, enc, x,
                                            w_f32, wgenW, wgenb, attn, pgen, ctx0, t == 0 ? 1 : 0,
                                            rowsum, argpk);
        k_vgemm<<<235, 256, 0, stream>>>(h_pk, emb_pk, E, rowsum, argpk);
        k_finalize<<<NR, 256, 0, stream>>>(E, pgen, rowsum, argpk, attn, x, embW, out,
                                           w_f32, w_hi, w_lo, ctx0, aW, ab, t);
    }
}

// Round 5
// 1096.926 us; speedup vs baseline: 1.1502x; 1.0151x over previous
//
#include <hip/hip_runtime.h>
#include <math.h>

#define V 30000
#define H 512
#define NB 16
#define NS 256
#define NJ 10
#define NT 8
#define NOPS 4
#define NR 160          // NJ*NB rows
#define EV 30720        // padded E row stride
#define NEGV -1e9f
#define NTILES 1875     // V/16 vocab n-tiles
#define NVB 235         // vgemm blocks (128 cols each)

typedef __attribute__((ext_vector_type(8))) short short8;
typedef __attribute__((ext_vector_type(4))) short short4v;
typedef __attribute__((ext_vector_type(4))) float f32x4;

__device__ inline float bf2f(unsigned short s) {
    union { unsigned int u; float f; } c; c.u = ((unsigned int)s) << 16;
    return c.f;
}
__device__ inline unsigned short f2bf(float f) {
    union { float f; unsigned int u; } c; c.f = f;
    unsigned int u = c.u;
    u += 0x7fffu + ((u >> 16) & 1u);   // RNE
    return (unsigned short)(u >> 16);
}
__device__ inline unsigned long long packkey(float f, int v) {
    union { float f; unsigned int u; } c; c.f = f;
    return ((unsigned long long)c.u << 32) | (unsigned int)(0x7FFFFFFF - v);
}

// ---------------- setup: pack emb_W into MFMA B-fragment order (bf16) ----------------
// emb_pk[((nt*16 + ks)*64 + lane)*8 + e] = emb[nt*16 + (lane&15)][ks*32 + (lane>>4)*8 + e]
// so a wave's B-fragment load for (nt, ks) is 64 consecutive short8s = 1KB fully coalesced.
__global__ __launch_bounds__(256) void k_setup_pack(const float* __restrict__ emb,
                                                    unsigned short* __restrict__ emb_pk) {
    __shared__ unsigned short L[16 * 512];
    int nt = blockIdx.x;          // 0..1874
    int t = threadIdx.x;
#pragma unroll
    for (int i = 0; i < 4; i++) {
        int o = i * 2048 + t * 8;
        int row = o >> 9, k = o & 511;
        const float4* src = (const float4*)(emb + (size_t)(nt * 16 + row) * 512 + k);
        float4 a = src[0], b = src[1];
        short8 v;
        v[0] = (short)f2bf(a.x); v[1] = (short)f2bf(a.y); v[2] = (short)f2bf(a.z); v[3] = (short)f2bf(a.w);
        v[4] = (short)f2bf(b.x); v[5] = (short)f2bf(b.y); v[6] = (short)f2bf(b.z); v[7] = (short)f2bf(b.w);
        *(short8*)(L + o) = v;
    }
    __syncthreads();
#pragma unroll
    for (int i = 0; i < 4; i++) {
        int idx = i * 256 + t;
        int ks = idx >> 6, l = idx & 63;
        int col15 = l & 15, quad = l >> 4;
        short8 v = *(const short8*)(L + col15 * 512 + ks * 32 + quad * 8);
        *(short8*)(emb_pk + ((size_t)(nt * 16 + ks) * 64 + l) * 8) = v;
    }
}

// ---------------- setup: W splits + initial w/h state (+ h_pk fragment layout) ----------------
__global__ void k_setup_small(const float* __restrict__ Wih, const float* __restrict__ Whh,
    unsigned short* wih_hi, unsigned short* wih_lo, unsigned short* whh_hi, unsigned short* whh_lo,
    const float* __restrict__ slot, const float* __restrict__ ench,
    float* w_g, unsigned short* w_hi, unsigned short* w_lo,
    float* h_g, unsigned short* h_hi, unsigned short* h_lo, unsigned short* h_pk)
{
    int gid = blockIdx.x * 256 + threadIdx.x;
    if (gid < 786432) {
        float v1 = Wih[gid];
        unsigned short hi = f2bf(v1);
        wih_hi[gid] = hi; wih_lo[gid] = f2bf(v1 - bf2f(hi));
        float v2 = Whh[gid];
        hi = f2bf(v2);
        whh_hi[gid] = hi; whh_lo[gid] = f2bf(v2 - bf2f(hi));
    } else {
        int i = gid - 786432;
        if (i < NR * H) {
            int jb = i >> 9, d = i & 511;
            int j = jb >> 4, b = jb & 15;
            float wv = slot[j * H + d];
            w_g[i] = wv;
            unsigned short hi = f2bf(wv);
            w_hi[i] = hi; w_lo[i] = f2bf(wv - bf2f(hi));
            float hv = ench[b * H + d];
            h_g[i] = hv;
            hi = f2bf(hv);
            h_hi[i] = hi; h_lo[i] = f2bf(hv - bf2f(hi));
            int ks = d >> 5, quad = (d >> 3) & 3, e = d & 7;
            h_pk[(((jb >> 4) * 16 + ks) * 64 + quad * 16 + (jb & 15)) * 8 + e] = hi;
        }
    }
}

// ---------------- GRU GEMMs: gi = w @ W_ih^T, gh = h @ W_hh^T (split-bf16, fp32-accurate) ----
#define GRU_APAD 520
__global__ __launch_bounds__(256) void k_gru_gemm(
    const unsigned short* __restrict__ w_hi, const unsigned short* __restrict__ w_lo,
    const unsigned short* __restrict__ h_hi, const unsigned short* __restrict__ h_lo,
    const unsigned short* __restrict__ wih_hi, const unsigned short* __restrict__ wih_lo,
    const unsigned short* __restrict__ whh_hi, const unsigned short* __restrict__ whh_lo,
    float* __restrict__ gi, float* __restrict__ gh)
{
    __shared__ unsigned short Ah[16 * GRU_APAD];
    __shared__ unsigned short Al[16 * GRU_APAD];
    int nch = blockIdx.x, mt = blockIdx.y, z = blockIdx.z;
    const unsigned short* Asrc_hi = z ? h_hi : w_hi;
    const unsigned short* Asrc_lo = z ? h_lo : w_lo;
    const unsigned short* Bhi = z ? whh_hi : wih_hi;
    const unsigned short* Blo = z ? whh_lo : wih_lo;
    float* outp = z ? gh : gi;
    int t = threadIdx.x;
    for (int i = t; i < 2048; i += 256) {
        int matl = i >> 10;
        int row = (i >> 6) & 15;
        int seg = i & 63;
        const unsigned short* src = (matl ? Asrc_lo : Asrc_hi) + (mt * 16 + row) * 512 + seg * 8;
        unsigned short* dst = (matl ? Al : Ah) + row * GRU_APAD + seg * 8;
        *(short8*)dst = *(const short8*)src;
    }
    __syncthreads();
    int wv = t >> 6, lane = t & 63;
    int col15 = lane & 15, quad = lane >> 4;
    f32x4 acc0 = {0.f, 0.f, 0.f, 0.f}, acc1 = {0.f, 0.f, 0.f, 0.f};
    int c0 = nch * 128 + wv * 32 + col15;
    int c1 = c0 + 16;
    const unsigned short* bhp0 = Bhi + c0 * 512 + quad * 8;
    const unsigned short* bhp1 = Bhi + c1 * 512 + quad * 8;
    const unsigned short* blp0 = Blo + c0 * 512 + quad * 8;
    const unsigned short* blp1 = Blo + c1 * 512 + quad * 8;
    const unsigned short* ahp = Ah + col15 * GRU_APAD + quad * 8;
    const unsigned short* alp = Al + col15 * GRU_APAD + quad * 8;
#pragma unroll
    for (int ks = 0; ks < 16; ks++) {
        int ko = ks * 32;
        short8 bh0 = *(const short8*)(bhp0 + ko);
        short8 bh1 = *(const short8*)(bhp1 + ko);
        short8 bl0 = *(const short8*)(blp0 + ko);
        short8 bl1 = *(const short8*)(blp1 + ko);
        short8 ah = *(const short8*)(ahp + ko);
        short8 al = *(const short8*)(alp + ko);
        acc0 = __builtin_amdgcn_mfma_f32_16x16x32_bf16(ah, bh0, acc0, 0, 0, 0);
        acc1 = __builtin_amdgcn_mfma_f32_16x16x32_bf16(ah, bh1, acc1, 0, 0, 0);
        acc0 = __builtin_amdgcn_mfma_f32_16x16x32_bf16(ah, bl0, acc0, 0, 0, 0);
        acc1 = __builtin_amdgcn_mfma_f32_16x16x32_bf16(ah, bl1, acc1, 0, 0, 0);
        acc0 = __builtin_amdgcn_mfma_f32_16x16x32_bf16(al, bh0, acc0, 0, 0, 0);
        acc1 = __builtin_amdgcn_mfma_f32_16x16x32_bf16(al, bh1, acc1, 0, 0, 0);
    }
#pragma unroll
    for (int r = 0; r < 4; r++) {
        int row = mt * 16 + quad * 4 + r;
        outp[row * 1536 + c0] = acc0[r];
        outp[row * 1536 + c1] = acc1[r];
    }
}

// --------- fused: GRU pointwise + attention scores + softmax + context + p_gen -------------
__global__ __launch_bounds__(256) void k_attention(
    const float* __restrict__ gi, const float* __restrict__ gh,
    const float* __restrict__ b_ih, const float* __restrict__ b_hh,
    float* __restrict__ h_g, unsigned short* __restrict__ h_hi, unsigned short* __restrict__ h_lo,
    unsigned short* __restrict__ h_pk,
    const float* __restrict__ enc, const int* __restrict__ x,
    const float* __restrict__ w_g, const float* __restrict__ wgenW, const float* __restrict__ wgenb,
    float* __restrict__ attn_g, float* __restrict__ pgen_g,
    float* __restrict__ ctx0, int store_ctx)
{
    __shared__ float h_lds[512];
    __shared__ float sc[256];
    __shared__ float red[256];
    __shared__ float ctxp[4 * 512];
    int jb = blockIdx.x;
    int b = jb & 15;
    int t = threadIdx.x;
    int m_pk = jb >> 4, c_pk = jb & 15;
    // GRU pointwise (PyTorch gate order r,z,n)
    for (int d = t; d < 512; d += 256) {
        int base = jb * 1536;
        float ir = gi[base + d]        + b_ih[d];
        float iz = gi[base + 512 + d]  + b_ih[512 + d];
        float in = gi[base + 1024 + d] + b_ih[1024 + d];
        float hr = gh[base + d]        + b_hh[d];
        float hz = gh[base + 512 + d]  + b_hh[512 + d];
        float hn = gh[base + 1024 + d] + b_hh[1024 + d];
        float hold = h_g[jb * 512 + d];
        float r = 1.f / (1.f + expf(-(ir + hr)));
        float z = 1.f / (1.f + expf(-(iz + hz)));
        float n = tanhf(in + r * hn);
        float hnew = (1.f - z) * n + z * hold;
        h_lds[d] = hnew;
        h_g[jb * 512 + d] = hnew;
        unsigned short hi = f2bf(hnew);
        h_hi[jb * 512 + d] = hi;
        h_lo[jb * 512 + d] = f2bf(hnew - bf2f(hi));
        int ks = d >> 5, quad = (d >> 3) & 3, e = d & 7;
        h_pk[((m_pk * 16 + ks) * 64 + quad * 16 + c_pk) * 8 + e] = hi;
    }
    __syncthreads();
    int wid = t >> 6, lane = t & 63;
    float hreg[8];
#pragma unroll
    for (int i = 0; i < 8; i++) hreg[i] = h_lds[lane * 8 + i];
    const float* encb = enc + (size_t)b * NS * H;
    for (int s = wid; s < NS; s += 4) {
        const float4* er = (const float4*)(encb + s * 512 + lane * 8);
        float4 e0 = er[0], e1 = er[1];
        float p = e0.x * hreg[0] + e0.y * hreg[1] + e0.z * hreg[2] + e0.w * hreg[3]
                + e1.x * hreg[4] + e1.y * hreg[5] + e1.z * hreg[6] + e1.w * hreg[7];
#pragma unroll
        for (int off = 32; off > 0; off >>= 1) p += __shfl_down(p, off);
        if (lane == 0) sc[s] = (x[b * NS + s] == 0) ? NEGV : p;
    }
    __syncthreads();
    // softmax over s
    red[t] = sc[t];
    __syncthreads();
    for (int sft = 128; sft > 0; sft >>= 1) { if (t < sft) red[t] = fmaxf(red[t], red[t + sft]); __syncthreads(); }
    float m = red[0];
    __syncthreads();
    float e = expf(sc[t] - m);
    red[t] = e;
    __syncthreads();
    for (int sft = 128; sft > 0; sft >>= 1) { if (t < sft) red[t] += red[t + sft]; __syncthreads(); }
    float inv = 1.f / red[0];
    float p_s = e * inv;
    sc[t] = p_s;
    attn_g[jb * NS + t] = p_s;
    __syncthreads();
    // context: wave `wid` covers s in [wid*64, wid*64+64), lane covers 8 dims
    {
        float cp[8] = {0.f,0.f,0.f,0.f,0.f,0.f,0.f,0.f};
        const float* encw = encb + lane * 8;
        for (int s = wid * 64; s < wid * 64 + 64; s++) {
            float ps = sc[s];
            const float4* er = (const float4*)(encw + s * 512);
            float4 e0 = er[0], e1 = er[1];
            cp[0] += ps * e0.x; cp[1] += ps * e0.y; cp[2] += ps * e0.z; cp[3] += ps * e0.w;
            cp[4] += ps * e1.x; cp[5] += ps * e1.y; cp[6] += ps * e1.z; cp[7] += ps * e1.w;
        }
        float* cw = ctxp + wid * 512 + lane * 8;
#pragma unroll
        for (int i = 0; i < 8; i++) cw[i] = cp[i];
    }
    __syncthreads();
    int d0 = 2 * t, d1 = 2 * t + 1;
    float c0 = ctxp[d0] + ctxp[512 + d0] + ctxp[1024 + d0] + ctxp[1536 + d0];
    float c1 = ctxp[d1] + ctxp[512 + d1] + ctxp[1024 + d1] + ctxp[1536 + d1];
    if (store_ctx) ((float2*)ctx0)[jb * 256 + t] = make_float2(c0, c1);
    float pg = wgenW[d0] * w_g[jb * 512 + d0] + wgenW[d1] * w_g[jb * 512 + d1]
             + wgenW[512 + d0] * h_lds[d0] + wgenW[512 + d1] * h_lds[d1]
             + wgenW[1024 + d0] * c0 + wgenW[1024 + d1] * c1;
    __syncthreads();
    red[t] = pg;
    __syncthreads();
    for (int sft = 128; sft > 0; sft >>= 1) { if (t < sft) red[t] += red[t + sft]; __syncthreads(); }
    if (t == 0) pgen_g[jb] = 1.f / (1.f + expf(-(red[0] + wgenb[0])));
}

// ------- vocab GEMM: packed-fragment operands (all loads coalesced). NO GLOBAL ATOMICS:
// per-block row partials (sum + argmax key) stored densely; k_finalize reduces them.
#define VPAD 136
__global__ __launch_bounds__(256) void k_vgemm(
    const unsigned short* __restrict__ h_pk, const unsigned short* __restrict__ emb_pk,
    unsigned short* __restrict__ E, float* __restrict__ rowsumP,
    unsigned long long* __restrict__ argpkP)
{
    __shared__ unsigned short A[160 * VPAD];   // 43520B; first 40960B reused as A-chunk stage
    int blk = blockIdx.x;
    int t = threadIdx.x;
    int wv = t >> 6, lane = t & 63, col15 = lane & 15, quad = lane >> 4;
    f32x4 acc[10][2];
#pragma unroll
    for (int m = 0; m < 10; m++) {
        acc[m][0] = (f32x4){0.f, 0.f, 0.f, 0.f};
        acc[m][1] = (f32x4){0.f, 0.f, 0.f, 0.f};
    }
    int nt0 = blk * 8 + wv * 2;
    int nt0c = min(nt0, NTILES - 1);
    int nt1c = min(nt0 + 1, NTILES - 1);
    for (int kc = 0; kc < 4; kc++) {
        __syncthreads();
        // stage A chunk: h_pk fragments for ks in [kc*4, kc*4+4), all 10 m-tiles (coalesced)
#pragma unroll
        for (int i = 0; i < 10; i++) {
            int o = i * 2048 + t * 8;          // element offset in 20480-element chunk
            int m = o >> 11, rem = o & 2047;
            *(short8*)(A + m * 2048 + rem) =
                *(const short8*)(h_pk + (size_t)(m * 16 + kc * 4) * 512 + rem);
        }
        __syncthreads();
#pragma unroll
        for (int q = 0; q < 4; q++) {
            int ksg = kc * 4 + q;
            short8 b0 = *(const short8*)(emb_pk + ((size_t)(nt0c * 16 + ksg) * 64 + lane) * 8);
            short8 b1 = *(const short8*)(emb_pk + ((size_t)(nt1c * 16 + ksg) * 64 + lane) * 8);
#pragma unroll
            for (int m = 0; m < 10; m++) {
                short8 a = *(const short8*)(A + m * 2048 + q * 512 + lane * 8);
                acc[m][0] = __builtin_amdgcn_mfma_f32_16x16x32_bf16(a, b0, acc[m][0], 0, 0, 0);
                acc[m][1] = __builtin_amdgcn_mfma_f32_16x16x32_bf16(a, b1, acc[m][1], 0, 0, 0);
            }
        }
    }
    __syncthreads();   // all LDS A reads done; reuse as transpose buffer
    // exp + transpose into LDS: A[row * VPAD + col_local] (bf16)
#pragma unroll
    for (int m = 0; m < 10; m++) {
#pragma unroll
        for (int tile = 0; tile < 2; tile++) {
            int cl = wv * 32 + tile * 16 + col15;
            int vv = blk * 128 + cl;
#pragma unroll
            for (int r = 0; r < 4; r++) {
                int row = m * 16 + quad * 4 + r;
                float ev = (vv < V) ? expf(acc[m][tile][r]) : 0.f;
                A[row * VPAD + cl] = f2bf(ev);
            }
        }
    }
    __syncthreads();
    // per-row sum + max over this block's 128 cols -> dense partial slots (no atomics)
    if (t < 160) {
        float s = 0.f;
        unsigned long long key = 0ull;
#pragma unroll
        for (int seg = 0; seg < 16; seg++) {
            short8 ev = *(const short8*)(A + t * VPAD + seg * 8);
#pragma unroll
            for (int k = 0; k < 8; k++) {
                float f = bf2f((unsigned short)ev[k]);
                s += f;
                unsigned long long kk = packkey(f, blk * 128 + seg * 8 + k);
                key = (kk > key) ? kk : key;
            }
        }
        rowsumP[t * NVB + blk] = s;
        argpkP[t * NVB + blk] = key;
    }
    // coalesced E store: 16 lanes per row (short8 each), 16 rows in flight, 10 iters
    {
        int rsub = t >> 4, seg = t & 15;
        for (int it = 0; it < 10; it++) {
            int row = it * 16 + rsub;
            short8 ev = *(const short8*)(A + row * VPAD + seg * 8);
            *(short8*)(E + (size_t)row * EV + blk * 128 + seg * 8) = ev;
        }
    }
}

// ------- finalize: reduce partials, scale+write dense, scatter, argmax, w_next, gates@t0 ---
__global__ __launch_bounds__(256) void k_finalize(
    const unsigned short* __restrict__ E, const float* __restrict__ pgen_g,
    const float* __restrict__ rowsumP, const unsigned long long* __restrict__ argpkP,
    const float* __restrict__ attn_g, const int* __restrict__ x,
    const float* __restrict__ emb, float* __restrict__ out,
    float* __restrict__ w_g, unsigned short* __restrict__ w_hi, unsigned short* __restrict__ w_lo,
    const float* __restrict__ ctx0, const float* __restrict__ aW, const float* __restrict__ ab,
    int tstep)
{
    __shared__ float bvs[256];
    __shared__ int bis[256];
    __shared__ float red[256];
    __shared__ unsigned long long kred[256];
    int jb = blockIdx.x, t = threadIdx.x;
    int j = jb >> 4, b = jb & 15;
    // deterministic reduction of per-block partials (replaces global atomics)
    red[t]  = (t < NVB) ? rowsumP[jb * NVB + t] : 0.f;
    kred[t] = (t < NVB) ? argpkP[jb * NVB + t] : 0ull;
    __syncthreads();
    for (int sft = 128; sft > 0; sft >>= 1) {
        if (t < sft) {
            red[t] += red[t + sft];
            if (kred[t + sft] > kred[t]) kred[t] = kred[t + sft];
        }
        __syncthreads();
    }
    float inv = 1.f / red[0];
    unsigned long long dkey = kred[0];
    float pgen = pgen_g[jb];
    float scale = pgen * inv;
    __syncthreads();
    const unsigned short* Er = E + (size_t)jb * EV;
    size_t outbase = (size_t)640 + ((size_t)(b * NJ + j) * NT + tstep) * V;
    float* op = out + outbase;
    // dense write: short8 loads, lane-consecutive float4 stores
    for (int c = 0; c < 14; c++) {
        int vv = c * 2048 + t * 8;
        short8 e = *(const short8*)(Er + vv);
        float4 p0 = make_float4(bf2f((unsigned short)e[0]) * scale, bf2f((unsigned short)e[1]) * scale,
                                bf2f((unsigned short)e[2]) * scale, bf2f((unsigned short)e[3]) * scale);
        float4 p1 = make_float4(bf2f((unsigned short)e[4]) * scale, bf2f((unsigned short)e[5]) * scale,
                                bf2f((unsigned short)e[6]) * scale, bf2f((unsigned short)e[7]) * scale);
        *(float4*)(op + vv) = p0;
        *(float4*)(op + vv + 4) = p1;
    }
    if (t < 166) {
        int vv = 28672 + t * 8;
        short8 e = *(const short8*)(Er + vv);
        float4 p0 = make_float4(bf2f((unsigned short)e[0]) * scale, bf2f((unsigned short)e[1]) * scale,
                                bf2f((unsigned short)e[2]) * scale, bf2f((unsigned short)e[3]) * scale);
        float4 p1 = make_float4(bf2f((unsigned short)e[4]) * scale, bf2f((unsigned short)e[5]) * scale,
                                bf2f((unsigned short)e[6]) * scale, bf2f((unsigned short)e[7]) * scale);
        *(float4*)(op + vv) = p0;
        *(float4*)(op + vv + 4) = p1;
    }
    __syncthreads();   // dense stores drained before scatter atomics
    // pointer scatter + candidate tracking (block-local region; atomics uncontended)
    float best; int besti;
    {
        int vv = x[b * NS + t];
        float a = (1.f - pgen) * attn_g[jb * NS + t];
        float old = atomicAdd(&op[vv], a);
        best = old + a;    // last adder to each vv sees the true final value
        besti = vv;
    }
    bvs[t] = best; bis[t] = besti;
    __syncthreads();
    for (int sft = 128; sft > 0; sft >>= 1) {
        if (t < sft) {
            if (bvs[t + sft] > bvs[t] || (bvs[t + sft] == bvs[t] && bis[t + sft] < bis[t])) {
                bvs[t] = bvs[t + sft]; bis[t] = bis[t + sft];
            }
        }
        __syncthreads();
    }
    // combine with dense argmax from vgemm partial-key reduction
    int widx;
    {
        union { unsigned int u; float f; } c; c.u = (unsigned int)(dkey >> 32);
        float db = c.f * scale;
        int di = 0x7FFFFFFF - (int)(dkey & 0xFFFFFFFFu);
        float sb = bvs[0]; int si = bis[0];
        widx = (sb > db || (sb == db && si < di)) ? si : di;
    }
    // w_next gather + bf16 split
    for (int d = t; d < 512; d += 256) {
        float val = emb[(size_t)widx * 512 + d];
        w_g[jb * 512 + d] = val;
        unsigned short hi = f2bf(val);
        w_hi[jb * 512 + d] = hi;
        w_lo[jb * 512 + d] = f2bf(val - bf2f(hi));
    }
    // gate head (uses step-0 context)
    if (tstep == 0) {
        float part[4] = {0.f, 0.f, 0.f, 0.f};
        for (int d = t; d < 512; d += 256) {
            float c = ctx0[jb * 512 + d];
#pragma unroll
            for (int o = 0; o < 4; o++) part[o] += c * aW[o * 512 + d];
        }
        for (int o = 0; o < 4; o++) {
            __syncthreads();
            red[t] = part[o];
            __syncthreads();
            for (int sft = 128; sft > 0; sft >>= 1) { if (t < sft) red[t] += red[t + sft]; __syncthreads(); }
            if (t == 0) out[(b * NJ + j) * NOPS + o] = red[0] + ab[o];
        }
    }
}

extern "C" void kernel_launch(void* const* d_in, const int* in_sizes, int n_in,
                              void* d_out, int out_size, void* d_ws, size_t ws_size,
                              hipStream_t stream) {
    const int*   x     = (const int*)d_in[0];
    const float* enc   = (const float*)d_in[1];
    const float* ench  = (const float*)d_in[2];
    const float* embW  = (const float*)d_in[4];
    const float* slot  = (const float*)d_in[5];
    const float* Wih   = (const float*)d_in[6];
    const float* Whh   = (const float*)d_in[7];
    const float* bih   = (const float*)d_in[8];
    const float* bhh   = (const float*)d_in[9];
    const float* wgenW = (const float*)d_in[10];
    const float* wgenb = (const float*)d_in[11];
    const float* aW    = (const float*)d_in[12];
    const float* ab    = (const float*)d_in[13];
    float* out = (float*)d_out;

    char* ws = (char*)d_ws;
    size_t off = 0;
    auto carve = [&](size_t bytes) { char* p = ws + off; off += (bytes + 255) & ~(size_t)255; return p; };
    unsigned short* emb_pk = (unsigned short*)carve((size_t)V * H * 2);
    unsigned short* wih_hi = (unsigned short*)carve(786432 * 2);
    unsigned short* wih_lo = (unsigned short*)carve(786432 * 2);
    unsigned short* whh_hi = (unsigned short*)carve(786432 * 2);
    unsigned short* whh_lo = (unsigned short*)carve(786432 * 2);
    float* w_f32 = (float*)carve(NR * H * 4);
    float* h_f32 = (float*)carve(NR * H * 4);
    float* ctx0  = (float*)carve(NR * H * 4);
    unsigned short* w_hi = (unsigned short*)carve(NR * H * 2);
    unsigned short* w_lo = (unsigned short*)carve(NR * H * 2);
    unsigned short* h_hi = (unsigned short*)carve(NR * H * 2);
    unsigned short* h_lo = (unsigned short*)carve(NR * H * 2);
    unsigned short* h_pk = (unsigned short*)carve(NR * H * 2);
    float* gi   = (float*)carve(NR * 1536 * 4);
    float* gh   = (float*)carve(NR * 1536 * 4);
    float* attn = (float*)carve(NR * NS * 4);
    float* pgen = (float*)carve(NR * 4);
    float* rowsumP = (float*)carve((size_t)NR * NVB * 4);
    unsigned long long* argpkP = (unsigned long long*)carve((size_t)NR * NVB * 8);
    unsigned short* E = (unsigned short*)carve((size_t)NR * EV * 2);

    k_setup_pack<<<NTILES, 256, 0, stream>>>(embW, emb_pk);
    k_setup_small<<<3392, 256, 0, stream>>>(Wih, Whh, wih_hi, wih_lo, whh_hi, whh_lo,
                                            slot, ench, w_f32, w_hi, w_lo, h_f32, h_hi, h_lo, h_pk);
    for (int t = 0; t < NT; t++) {
        k_gru_gemm<<<dim3(12, 10, 2), 256, 0, stream>>>(w_hi, w_lo, h_hi, h_lo,
                                                        wih_hi, wih_lo, whh_hi, whh_lo, gi, gh);
        k_attention<<<NR, 256, 0, stream>>>(gi, gh, bih, bhh, h_f32, h_hi, h_lo, h_pk, enc, x,
                                            w_f32, wgenW, wgenb, attn, pgen, ctx0, t == 0 ? 1 : 0);
        k_vgemm<<<NVB, 256, 0, stream>>>(h_pk, emb_pk, E, rowsumP, argpkP);
        k_finalize<<<NR, 256, 0, stream>>>(E, pgen, rowsumP, argpkP, attn, x, embW, out,
                                           w_f32, w_hi, w_lo, ctx0, aW, ab, t);
    }
}